// Round 6
// baseline (365.277 us; speedup 1.0000x reference)
//
#include <hip/hip_runtime.h>

#define HIDDEN 1024
#define SEQ 2048
#define NB 2

typedef _Float16 half8 __attribute__((ext_vector_type(8)));
typedef _Float16 half4 __attribute__((ext_vector_type(4)));
typedef float f32x4 __attribute__((ext_vector_type(4)));

// ---------------- cast x fp32 -> fp16 ----------------
__global__ __launch_bounds__(256) void cast_x(const float* __restrict__ x,
                                              _Float16* __restrict__ xh, int n) {
    int i = (blockIdx.x * 256 + threadIdx.x) * 4;
    if (i < n) {
        float4 v = *(const float4*)(x + i);
        half4 h;
        h[0] = (_Float16)v.x; h[1] = (_Float16)v.y;
        h[2] = (_Float16)v.z; h[3] = (_Float16)v.w;
        *(half4*)(xh + i) = h;
    }
}

// ---------------- cast + transpose Wq: wt[n][k] = Wq[k][n] ----------------
__global__ __launch_bounds__(256) void cast_wt(const float* __restrict__ w,
                                               _Float16* __restrict__ wt) {
    __shared__ float tile[32][33];
    int bx = blockIdx.x * 32, by = blockIdx.y * 32;
    int tx = threadIdx.x, ty = threadIdx.y;   // (32, 8)
    #pragma unroll
    for (int i = 0; i < 32; i += 8)
        tile[ty + i][tx] = w[(by + ty + i) * HIDDEN + bx + tx];
    __syncthreads();
    #pragma unroll
    for (int i = 0; i < 32; i += 8)
        wt[(bx + ty + i) * HIDDEN + by + tx] = (_Float16)tile[tx][ty + i];
}

// ---------------- projection GEMM: Q = x @ Wq + bq  (fp16 in/out, fp32 acc) ----------------
__global__ __launch_bounds__(256) void proj_gemm(const _Float16* __restrict__ A,
                                                 const _Float16* __restrict__ Bt,
                                                 const float* __restrict__ bias,
                                                 _Float16* __restrict__ Q) {
    __shared__ _Float16 As[128][72];
    __shared__ _Float16 Bs[128][72];
    const int m0 = blockIdx.x * 128;
    const int n0 = blockIdx.y * 128;
    const int tid = threadIdx.x;
    const int w = tid >> 6, l = tid & 63;
    const int wm = w >> 1, wn = w & 1;           // 2x2 waves, each 64x64
    const int lrow = l & 15, lk = (l >> 4) * 8;

    f32x4 acc[4][4] = {};

    for (int k0 = 0; k0 < HIDDEN; k0 += 64) {
        __syncthreads();
        #pragma unroll
        for (int i = 0; i < 4; ++i) {
            int id = tid + i * 256;
            int r = id >> 3, c = id & 7;
            *(half8*)&As[r][c * 8] = *(const half8*)&A[(size_t)(m0 + r) * HIDDEN + k0 + c * 8];
        }
        #pragma unroll
        for (int i = 0; i < 4; ++i) {
            int id = tid + i * 256;
            int r = id >> 3, c = id & 7;
            *(half8*)&Bs[r][c * 8] = *(const half8*)&Bt[(size_t)(n0 + r) * HIDDEN + k0 + c * 8];
        }
        __syncthreads();
        #pragma unroll
        for (int kk = 0; kk < 64; kk += 32) {
            half8 af[4], bf[4];
            #pragma unroll
            for (int m = 0; m < 4; ++m)
                af[m] = *(const half8*)&As[wm * 64 + m * 16 + lrow][kk + lk];
            #pragma unroll
            for (int n = 0; n < 4; ++n)
                bf[n] = *(const half8*)&Bs[wn * 64 + n * 16 + lrow][kk + lk];
            #pragma unroll
            for (int m = 0; m < 4; ++m)
                #pragma unroll
                for (int n = 0; n < 4; ++n)
                    acc[m][n] = __builtin_amdgcn_mfma_f32_16x16x32_f16(af[m], bf[n], acc[m][n], 0, 0, 0);
        }
    }
    const int lr4 = (l >> 4) * 4, lc = l & 15;
    #pragma unroll
    for (int n = 0; n < 4; ++n) {
        int gcol = n0 + wn * 64 + n * 16 + lc;
        float b = bias[gcol];
        #pragma unroll
        for (int m = 0; m < 4; ++m) {
            #pragma unroll
            for (int r = 0; r < 4; ++r) {
                int grow = m0 + wm * 64 + m * 16 + lr4 + r;
                Q[(size_t)grow * HIDDEN + gcol] = (_Float16)(acc[m][n][r] + b);
            }
        }
    }
}

// ---------------- fused scores + softmax: p in registers, loads-then-stores ----------------
// Block = 256 thr = 4 waves = one 16q x 2048k strip of one (b,h). Wave w owns
// k in [w*512, w*512+512): 32 MFMA frag-pairs; p = exp2(e*0.125*log2e - 8*log2e)
// packed fp16 into 32 half4 regs (static idx). VMEM stream is loads-only until
// the single rsum barrier, then 32 independent plain f32x4 stores and exit --
// no load ever waits behind a store in the in-order vmcnt queue.
__global__ __launch_bounds__(256, 4) void scores_softmax(const _Float16* __restrict__ Qh,
                                                         float* __restrict__ out) {
    __shared__ float rsum_lds[4][16];

    // chunked XCD swizzle (4096 blocks, 8 XCDs): each XCD gets 4 consecutive
    // (b,h) slices -> 1 MB K working set per XCD L2.
    const int raw = blockIdx.x;
    const int bid = (raw & 7) * 512 + (raw >> 3);
    const int bh = bid >> 7;           // 0..31
    const int qb = bid & 127;          // 0..127
    const int b = bh >> 4, h = bh & 15;

    const int tid = threadIdx.x;
    const int w = tid >> 6;            // wave 0..3
    const int l = tid & 63;
    const int lq = l & 15, lg = l >> 4;
    const int q0 = qb * 16;
    const int hoff = h * 64;
    const _Float16* qbase = Qh + (size_t)b * SEQ * HIDDEN;

    // Q fragments (B operand): lane&15 = q-row, lg*8 = d-offset
    const _Float16* qp = qbase + (size_t)(q0 + lq) * HIDDEN + hoff + lg * 8;
    const half8 bq0 = *(const half8*)qp;
    const half8 bq1 = *(const half8*)(qp + 32);

    // K fragment base (A operand) for this wave's k-range
    const _Float16* kbase = qbase + (size_t)(w * 512 + lq) * HIDDEN + hoff + lg * 8;

    half4 pv[32];
    float rsum = 0.f;

    half8 ka = *(const half8*)kbase;
    half8 kb = *(const half8*)(kbase + 32);
    #pragma unroll
    for (int s = 0; s < 32; ++s) {
        // prefetch next frag (clamped dummy reload at s=31; L2-hit, harmless)
        const int sn = (s < 31) ? s + 1 : 0;
        const _Float16* a = kbase + (size_t)sn * 16 * HIDDEN;
        half8 na = *(const half8*)a;
        half8 nb = *(const half8*)(a + 32);

        f32x4 acc = {};
        acc = __builtin_amdgcn_mfma_f32_16x16x32_f16(ka, bq0, acc, 0, 0, 0);
        acc = __builtin_amdgcn_mfma_f32_16x16x32_f16(kb, bq1, acc, 0, 0, 0);
        // C layout: col(q)=lane&15, row(k)=lg*4+reg
        float e0 = exp2f(fmaf(acc[0], 0.18033688011f, -11.54156033f));
        float e1 = exp2f(fmaf(acc[1], 0.18033688011f, -11.54156033f));
        float e2 = exp2f(fmaf(acc[2], 0.18033688011f, -11.54156033f));
        float e3 = exp2f(fmaf(acc[3], 0.18033688011f, -11.54156033f));
        rsum += (e0 + e1) + (e2 + e3);
        half4 hv;
        hv[0] = (_Float16)e0; hv[1] = (_Float16)e1;
        hv[2] = (_Float16)e2; hv[3] = (_Float16)e3;
        pv[s] = hv;
        ka = na; kb = nb;
    }

    // per-wave fold of the 4 lane-groups, then cross-wave via tiny LDS
    rsum += __shfl_xor(rsum, 16);
    rsum += __shfl_xor(rsum, 32);
    if (l < 16) rsum_lds[w][l] = rsum;
    __syncthreads();   // no global stores outstanding -> cheap drain
    const float rs = rsum_lds[0][lq] + rsum_lds[1][lq] + rsum_lds[2][lq] + rsum_lds[3][lq];
    const float rinv = 1.0f / rs;

    // ---- store burst: 32 independent f32x4 plain stores, then exit ----
    float* orow = out + (size_t)(b * 16 + h) * SEQ * SEQ
                      + (size_t)(q0 + lq) * SEQ + w * 512 + lg * 4;
    #pragma unroll
    for (int s = 0; s < 32; ++s) {
        f32x4 v;
        v[0] = (float)pv[s][0] * rinv;
        v[1] = (float)pv[s][1] * rinv;
        v[2] = (float)pv[s][2] * rinv;
        v[3] = (float)pv[s][3] * rinv;
        *(f32x4*)(orow + s * 16) = v;
    }
}

extern "C" void kernel_launch(void* const* d_in, const int* in_sizes, int n_in,
                              void* d_out, int out_size, void* d_ws, size_t ws_size,
                              hipStream_t stream) {
    const float* x  = (const float*)d_in[0];   // [2,2048,1024]
    const float* Wq = (const float*)d_in[1];   // [1024,1024]
    const float* bq = (const float*)d_in[2];   // [1024]
    float* out = (float*)d_out;                // [2,16,2048,2048]

    _Float16* xh = (_Float16*)d_ws;                    // 8 MB
    _Float16* qh = xh + (size_t)4 * 1024 * 1024;       // 8 MB
    _Float16* wt = qh + (size_t)4 * 1024 * 1024;       // 2 MB

    const int nx = NB * SEQ * HIDDEN;  // 4194304
    cast_x<<<nx / (256 * 4), 256, 0, stream>>>(x, xh, nx);
    cast_wt<<<dim3(32, 32), dim3(32, 8), 0, stream>>>(Wq, wt);
    proj_gemm<<<dim3(NB * SEQ / 128, HIDDEN / 128), 256, 0, stream>>>(xh, wt, bq, qh);
    scores_softmax<<<NB * 16 * (SEQ / 16), 256, 0, stream>>>(qh, out);
}

// Round 7
// 133.806 us; speedup vs baseline: 2.7299x; 2.7299x over previous
//
#include <hip/hip_runtime.h>

#define HIDDEN 1024
#define SEQ 2048
#define NB 2
#define PSTRIDE 2052  // halfs per LDS p-row: 2048 + 4 pad
#define NT 16         // strips per block

typedef _Float16 half8 __attribute__((ext_vector_type(8)));
typedef _Float16 half4 __attribute__((ext_vector_type(4)));
typedef float f32x4 __attribute__((ext_vector_type(4)));

// ---------------- cast x fp32 -> fp16 ----------------
__global__ __launch_bounds__(256) void cast_x(const float* __restrict__ x,
                                              _Float16* __restrict__ xh, int n) {
    int i = (blockIdx.x * 256 + threadIdx.x) * 4;
    if (i < n) {
        float4 v = *(const float4*)(x + i);
        half4 h;
        h[0] = (_Float16)v.x; h[1] = (_Float16)v.y;
        h[2] = (_Float16)v.z; h[3] = (_Float16)v.w;
        *(half4*)(xh + i) = h;
    }
}

// ---------------- cast + transpose Wq: wt[n][k] = Wq[k][n] ----------------
__global__ __launch_bounds__(256) void cast_wt(const float* __restrict__ w,
                                               _Float16* __restrict__ wt) {
    __shared__ float tile[32][33];
    int bx = blockIdx.x * 32, by = blockIdx.y * 32;
    int tx = threadIdx.x, ty = threadIdx.y;   // (32, 8)
    #pragma unroll
    for (int i = 0; i < 32; i += 8)
        tile[ty + i][tx] = w[(by + ty + i) * HIDDEN + bx + tx];
    __syncthreads();
    #pragma unroll
    for (int i = 0; i < 32; i += 8)
        wt[(bx + ty + i) * HIDDEN + by + tx] = (_Float16)tile[tx][ty + i];
}

// ---------------- projection GEMM: Q = x @ Wq + bq  (fp16 in/out, fp32 acc) ----------------
__global__ __launch_bounds__(256) void proj_gemm(const _Float16* __restrict__ A,
                                                 const _Float16* __restrict__ Bt,
                                                 const float* __restrict__ bias,
                                                 _Float16* __restrict__ Q) {
    __shared__ _Float16 As[128][72];
    __shared__ _Float16 Bs[128][72];
    const int m0 = blockIdx.x * 128;
    const int n0 = blockIdx.y * 128;
    const int tid = threadIdx.x;
    const int w = tid >> 6, l = tid & 63;
    const int wm = w >> 1, wn = w & 1;           // 2x2 waves, each 64x64
    const int lrow = l & 15, lk = (l >> 4) * 8;

    f32x4 acc[4][4] = {};

    for (int k0 = 0; k0 < HIDDEN; k0 += 64) {
        __syncthreads();
        #pragma unroll
        for (int i = 0; i < 4; ++i) {
            int id = tid + i * 256;
            int r = id >> 3, c = id & 7;
            *(half8*)&As[r][c * 8] = *(const half8*)&A[(size_t)(m0 + r) * HIDDEN + k0 + c * 8];
        }
        #pragma unroll
        for (int i = 0; i < 4; ++i) {
            int id = tid + i * 256;
            int r = id >> 3, c = id & 7;
            *(half8*)&Bs[r][c * 8] = *(const half8*)&Bt[(size_t)(n0 + r) * HIDDEN + k0 + c * 8];
        }
        __syncthreads();
        #pragma unroll
        for (int kk = 0; kk < 64; kk += 32) {
            half8 af[4], bf[4];
            #pragma unroll
            for (int m = 0; m < 4; ++m)
                af[m] = *(const half8*)&As[wm * 64 + m * 16 + lrow][kk + lk];
            #pragma unroll
            for (int n = 0; n < 4; ++n)
                bf[n] = *(const half8*)&Bs[wn * 64 + n * 16 + lrow][kk + lk];
            #pragma unroll
            for (int m = 0; m < 4; ++m)
                #pragma unroll
                for (int n = 0; n < 4; ++n)
                    acc[m][n] = __builtin_amdgcn_mfma_f32_16x16x32_f16(af[m], bf[n], acc[m][n], 0, 0, 0);
        }
    }
    const int lr4 = (l >> 4) * 4, lc = l & 15;
    #pragma unroll
    for (int n = 0; n < 4; ++n) {
        int gcol = n0 + wn * 64 + n * 16 + lc;
        float b = bias[gcol];
        #pragma unroll
        for (int m = 0; m < 4; ++m) {
            #pragma unroll
            for (int r = 0; r < 4; ++r) {
                int grow = m0 + wm * 64 + m * 16 + lr4 + r;
                Q[(size_t)grow * HIDDEN + gcol] = (_Float16)(acc[m][n][r] + b);
            }
        }
    }
}

// ---------------- fused scores + softmax: producer/consumer wave specialization ----------------
// 256 blocks (1/CU) x 1024 thr = 16 waves. Waves 0-7 PRODUCE: global K/Q loads
// -> MFMA -> exp -> fp16 pack -> ds_write into double-buffered 16x2048 p-tile.
// Waves 8-15 CONSUME: ds_read -> *rinv -> contiguous non-temporal f32x4 stores
// (1 KB/wave-instr, L2-bypassing). vmcnt is per-wave: producers' load waits
// never sit behind stores; consumers never wait vmcnt at all. Phases linked by
// lgkmcnt(0)+s_barrier only, so NT stores drain across the next strip's compute.
// p = exp(e/8 - 8); the shift cancels in normalization.
__global__ __launch_bounds__(1024, 4) void scores_softmax(const _Float16* __restrict__ Qh,
                                                          float* __restrict__ out) {
    __shared__ __align__(16) _Float16 p[2][16][PSTRIDE];
    __shared__ float rsum_lds[2][8][16];

    // raw&7 = XCD (round-robin dispatch assumption): all 8 q-chunks of a (b,h)
    // land on one XCD; 4 slices x 256 KB = 1 MB per XCD L2, never store-thrashed.
    const int raw = blockIdx.x;            // 0..255
    const int xcd = raw & 7, i = raw >> 3; // i: 0..31
    const int bh = xcd * 4 + (i >> 3);     // 0..31
    const int qchunk = i & 7;              // rows [qchunk*256, +256)
    const int b = bh >> 4, h = bh & 15;

    const int tid = threadIdx.x;
    const int wv = tid >> 6;               // 0..15
    const int l = tid & 63;
    const int lq = l & 15, lg = l >> 4;
    const int hoff = h * 64;
    const _Float16* qbase = Qh + (size_t)b * SEQ * HIDDEN;
    const size_t outbase = (size_t)(b * 16 + h) * SEQ * SEQ;

    if (wv < 8) {
        // ================= PRODUCER (waves 0-7) =================
        const int pw = wv;
        // K frag base for this wave's k-range [pw*256, +256)
        const _Float16* kbase = qbase + (size_t)(pw * 256 + lq) * HIDDEN + hoff + lg * 8;
        for (int t = 0; t <= NT; ++t) {
            if (t < NT) {
                const int buf = t & 1;
                const int q0 = qchunk * 256 + t * 16;
                const _Float16* qp = qbase + (size_t)(q0 + lq) * HIDDEN + hoff + lg * 8;
                const half8 bq0 = *(const half8*)qp;
                const half8 bq1 = *(const half8*)(qp + 32);
                float rsum = 0.f;
                #pragma unroll
                for (int s = 0; s < 16; ++s) {
                    const _Float16* a = kbase + (size_t)s * 16 * HIDDEN;
                    half8 ka = *(const half8*)a;
                    half8 kb = *(const half8*)(a + 32);
                    f32x4 acc = {};
                    acc = __builtin_amdgcn_mfma_f32_16x16x32_f16(ka, bq0, acc, 0, 0, 0);
                    acc = __builtin_amdgcn_mfma_f32_16x16x32_f16(kb, bq1, acc, 0, 0, 0);
                    // C layout: col(q)=lane&15, row(k)=lg*4+reg
                    float e0 = exp2f(fmaf(acc[0], 0.18033688011f, -11.54156033f));
                    float e1 = exp2f(fmaf(acc[1], 0.18033688011f, -11.54156033f));
                    float e2 = exp2f(fmaf(acc[2], 0.18033688011f, -11.54156033f));
                    float e3 = exp2f(fmaf(acc[3], 0.18033688011f, -11.54156033f));
                    rsum += (e0 + e1) + (e2 + e3);
                    half4 hv;
                    hv[0] = (_Float16)e0; hv[1] = (_Float16)e1;
                    hv[2] = (_Float16)e2; hv[3] = (_Float16)e3;
                    *(half4*)&p[buf][lq][pw * 256 + s * 16 + lg * 4] = hv;
                }
                rsum += __shfl_xor(rsum, 16);
                rsum += __shfl_xor(rsum, 32);
                if (l < 16) rsum_lds[buf][pw][l] = rsum;
            }
            asm volatile("s_waitcnt lgkmcnt(0)" ::: "memory");
            __builtin_amdgcn_s_barrier();
        }
    } else {
        // ================= CONSUMER (waves 8-15) =================
        const int cw = wv - 8;             // rows 2cw, 2cw+1 of each strip
        for (int t = 0; t <= NT; ++t) {
            if (t > 0) {
                const int pbuf = (t - 1) & 1;
                #pragma unroll
                for (int rr = 0; rr < 2; ++rr) {
                    const int r = cw * 2 + rr;
                    float rs = 0.f;
                    #pragma unroll
                    for (int w8 = 0; w8 < 8; ++w8) rs += rsum_lds[pbuf][w8][r];
                    const float rinv = 1.0f / rs;
                    float* orow = out + outbase
                                + (size_t)(qchunk * 256 + (t - 1) * 16 + r) * SEQ;
                    #pragma unroll
                    for (int ii = 0; ii < 8; ++ii) {
                        half4 hv = *(const half4*)&p[pbuf][r][ii * 256 + l * 4];
                        f32x4 v;
                        v[0] = (float)hv[0] * rinv; v[1] = (float)hv[1] * rinv;
                        v[2] = (float)hv[2] * rinv; v[3] = (float)hv[3] * rinv;
                        __builtin_nontemporal_store(v, (f32x4*)(orow + ii * 256 + l * 4));
                    }
                }
            }
            asm volatile("s_waitcnt lgkmcnt(0)" ::: "memory");
            __builtin_amdgcn_s_barrier();
        }
    }
}

extern "C" void kernel_launch(void* const* d_in, const int* in_sizes, int n_in,
                              void* d_out, int out_size, void* d_ws, size_t ws_size,
                              hipStream_t stream) {
    const float* x  = (const float*)d_in[0];   // [2,2048,1024]
    const float* Wq = (const float*)d_in[1];   // [1024,1024]
    const float* bq = (const float*)d_in[2];   // [1024]
    float* out = (float*)d_out;                // [2,16,2048,2048]

    _Float16* xh = (_Float16*)d_ws;                    // 8 MB
    _Float16* qh = xh + (size_t)4 * 1024 * 1024;       // 8 MB
    _Float16* wt = qh + (size_t)4 * 1024 * 1024;       // 2 MB

    const int nx = NB * SEQ * HIDDEN;  // 4194304
    cast_x<<<nx / (256 * 4), 256, 0, stream>>>(x, xh, nx);
    cast_wt<<<dim3(32, 32), dim3(32, 8), 0, stream>>>(Wq, wt);
    proj_gemm<<<dim3(NB * SEQ / 128, HIDDEN / 128), 256, 0, stream>>>(xh, wt, bq, qh);
    scores_softmax<<<256, 1024, 0, stream>>>(qh, out);
}

// Round 8
// 131.360 us; speedup vs baseline: 2.7807x; 1.0186x over previous
//
#include <hip/hip_runtime.h>

#define HIDDEN 1024
#define SEQ 2048
#define NB 2
#define PSTRIDE 2052  // halfs per LDS p-row: 2048 + 4 pad
#define NT 16         // strips per block

typedef _Float16 half8 __attribute__((ext_vector_type(8)));
typedef _Float16 half4 __attribute__((ext_vector_type(4)));
typedef float f32x4 __attribute__((ext_vector_type(4)));

// global -> LDS direct staging, 16 B/lane (dest = wave-uniform base + lane*16)
#define GL2LDS(gp, lp) __builtin_amdgcn_global_load_lds( \
    (const __attribute__((address_space(1))) void*)(gp), \
    (__attribute__((address_space(3))) void*)(lp), 16, 0, 0)

// ---------------- cast x fp32 -> fp16 ----------------
__global__ __launch_bounds__(256) void cast_x(const float* __restrict__ x,
                                              _Float16* __restrict__ xh, int n) {
    int i = (blockIdx.x * 256 + threadIdx.x) * 4;
    if (i < n) {
        float4 v = *(const float4*)(x + i);
        half4 h;
        h[0] = (_Float16)v.x; h[1] = (_Float16)v.y;
        h[2] = (_Float16)v.z; h[3] = (_Float16)v.w;
        *(half4*)(xh + i) = h;
    }
}

// ---------------- cast + transpose Wq: wt[n][k] = Wq[k][n] ----------------
__global__ __launch_bounds__(256) void cast_wt(const float* __restrict__ w,
                                               _Float16* __restrict__ wt) {
    __shared__ float tile[32][33];
    int bx = blockIdx.x * 32, by = blockIdx.y * 32;
    int tx = threadIdx.x, ty = threadIdx.y;   // (32, 8)
    #pragma unroll
    for (int i = 0; i < 32; i += 8)
        tile[ty + i][tx] = w[(by + ty + i) * HIDDEN + bx + tx];
    __syncthreads();
    #pragma unroll
    for (int i = 0; i < 32; i += 8)
        wt[(bx + ty + i) * HIDDEN + by + tx] = (_Float16)tile[tx][ty + i];
}

// ---------------- projection GEMM: Q = x @ Wq + bq ----------------
// 128x128 tile, BK=64, 512 thr = 8 waves (2x4, wave-tile 64x32).
// Staging via global_load_lds width=16 into LINEAR LDS [128][64] halfs;
// bank-conflict fix by pre-swizzling the GLOBAL source slot (slot ^= row&7)
// and applying the same XOR on the ds_read side (both-sides-or-neither).
__global__ __launch_bounds__(512) void proj_gemm(const _Float16* __restrict__ A,
                                                 const _Float16* __restrict__ Bt,
                                                 const float* __restrict__ bias,
                                                 _Float16* __restrict__ Q) {
    __shared__ _Float16 As[128 * 64];
    __shared__ _Float16 Bs[128 * 64];
    const int m0 = blockIdx.x * 128;
    const int n0 = blockIdx.y * 128;
    const int tid = threadIdx.x;
    const int w = tid >> 6, l = tid & 63;
    const int wm = w >> 2, wn = w & 3;           // 2x4 waves: 64-row x 32-col tiles
    const int lrow = l & 15, lkslot = l >> 4;    // frag: k-offset = lkslot*8

    // staging coords: within a 1 KB chunk (8 rows x 64 halfs), lane l covers
    // row chunk*8 + l/8, 16B slot l%8.
    const int srow = l >> 3, sslot = l & 7;

    f32x4 acc[4][2] = {};

    for (int k0 = 0; k0 < HIDDEN; k0 += 64) {
        __syncthreads();
        #pragma unroll
        for (int j = 0; j < 2; ++j) {
            const int chunk = w * 2 + j;              // 0..15
            const int r = chunk * 8 + srow;           // 0..127
            const int gslot = sslot ^ (r & 7);        // pre-swizzled source
            GL2LDS(&A[(size_t)(m0 + r) * HIDDEN + k0 + gslot * 8], As + chunk * 512);
            GL2LDS(&Bt[(size_t)(n0 + r) * HIDDEN + k0 + gslot * 8], Bs + chunk * 512);
        }
        __syncthreads();   // compiler emits vmcnt(0) drain for the LDS loads
        #pragma unroll
        for (int kk = 0; kk < 64; kk += 32) {
            const int csb = kk >> 3;                  // 0 or 4
            half8 af[4], bf[2];
            #pragma unroll
            for (int m = 0; m < 4; ++m) {
                const int R = wm * 64 + m * 16 + lrow;
                const int slot = (csb + lkslot) ^ (R & 7);
                af[m] = *(const half8*)&As[R * 64 + slot * 8];
            }
            #pragma unroll
            for (int n = 0; n < 2; ++n) {
                const int R = wn * 32 + n * 16 + lrow;
                const int slot = (csb + lkslot) ^ (R & 7);
                bf[n] = *(const half8*)&Bs[R * 64 + slot * 8];
            }
            #pragma unroll
            for (int m = 0; m < 4; ++m)
                #pragma unroll
                for (int n = 0; n < 2; ++n)
                    acc[m][n] = __builtin_amdgcn_mfma_f32_16x16x32_f16(af[m], bf[n], acc[m][n], 0, 0, 0);
        }
    }
    const int lr4 = (l >> 4) * 4, lc = l & 15;
    #pragma unroll
    for (int n = 0; n < 2; ++n) {
        int gcol = n0 + wn * 32 + n * 16 + lc;
        float b = bias[gcol];
        #pragma unroll
        for (int m = 0; m < 4; ++m) {
            #pragma unroll
            for (int r = 0; r < 4; ++r) {
                int grow = m0 + wm * 64 + m * 16 + lr4 + r;
                Q[(size_t)grow * HIDDEN + gcol] = (_Float16)(acc[m][n][r] + b);
            }
        }
    }
}

// ---------------- fused scores + softmax: producer/consumer wave specialization ----------------
// 256 blocks (1/CU) x 1024 thr = 16 waves. Waves 0-7 PRODUCE: global K/Q loads
// -> MFMA -> exp -> fp16 pack -> ds_write into double-buffered 16x2048 p-tile.
// Waves 8-15 CONSUME: ds_read -> *rinv -> contiguous non-temporal f32x4 stores
// (1 KB/wave-instr, L2-bypassing). vmcnt is per-wave: producers' load waits
// never sit behind stores; consumers never wait vmcnt at all. Phases linked by
// lgkmcnt(0)+s_barrier only, so NT stores drain across the next strip's compute.
// p = exp(e/8 - 8); the shift cancels in normalization.
__global__ __launch_bounds__(1024, 4) void scores_softmax(const _Float16* __restrict__ Qh,
                                                          float* __restrict__ out) {
    __shared__ __align__(16) _Float16 p[2][16][PSTRIDE];
    __shared__ float rsum_lds[2][8][16];

    // raw&7 = XCD (round-robin dispatch assumption): all 8 q-chunks of a (b,h)
    // land on one XCD; 4 slices x 256 KB = 1 MB per XCD L2, never store-thrashed.
    const int raw = blockIdx.x;            // 0..255
    const int xcd = raw & 7, i = raw >> 3; // i: 0..31
    const int bh = xcd * 4 + (i >> 3);     // 0..31
    const int qchunk = i & 7;              // rows [qchunk*256, +256)
    const int b = bh >> 4, h = bh & 15;

    const int tid = threadIdx.x;
    const int wv = tid >> 6;               // 0..15
    const int l = tid & 63;
    const int lq = l & 15, lg = l >> 4;
    const int hoff = h * 64;
    const _Float16* qbase = Qh + (size_t)b * SEQ * HIDDEN;
    const size_t outbase = (size_t)(b * 16 + h) * SEQ * SEQ;

    if (wv < 8) {
        // ================= PRODUCER (waves 0-7) =================
        const int pw = wv;
        const _Float16* kbase = qbase + (size_t)(pw * 256 + lq) * HIDDEN + hoff + lg * 8;
        for (int t = 0; t <= NT; ++t) {
            if (t < NT) {
                const int buf = t & 1;
                const int q0 = qchunk * 256 + t * 16;
                const _Float16* qp = qbase + (size_t)(q0 + lq) * HIDDEN + hoff + lg * 8;
                const half8 bq0 = *(const half8*)qp;
                const half8 bq1 = *(const half8*)(qp + 32);
                float rsum = 0.f;
                #pragma unroll
                for (int s = 0; s < 16; ++s) {
                    const _Float16* a = kbase + (size_t)s * 16 * HIDDEN;
                    half8 ka = *(const half8*)a;
                    half8 kb = *(const half8*)(a + 32);
                    f32x4 acc = {};
                    acc = __builtin_amdgcn_mfma_f32_16x16x32_f16(ka, bq0, acc, 0, 0, 0);
                    acc = __builtin_amdgcn_mfma_f32_16x16x32_f16(kb, bq1, acc, 0, 0, 0);
                    // C layout: col(q)=lane&15, row(k)=lg*4+reg
                    float e0 = exp2f(fmaf(acc[0], 0.18033688011f, -11.54156033f));
                    float e1 = exp2f(fmaf(acc[1], 0.18033688011f, -11.54156033f));
                    float e2 = exp2f(fmaf(acc[2], 0.18033688011f, -11.54156033f));
                    float e3 = exp2f(fmaf(acc[3], 0.18033688011f, -11.54156033f));
                    rsum += (e0 + e1) + (e2 + e3);
                    half4 hv;
                    hv[0] = (_Float16)e0; hv[1] = (_Float16)e1;
                    hv[2] = (_Float16)e2; hv[3] = (_Float16)e3;
                    *(half4*)&p[buf][lq][pw * 256 + s * 16 + lg * 4] = hv;
                }
                rsum += __shfl_xor(rsum, 16);
                rsum += __shfl_xor(rsum, 32);
                if (l < 16) rsum_lds[buf][pw][l] = rsum;
            }
            asm volatile("s_waitcnt lgkmcnt(0)" ::: "memory");
            __builtin_amdgcn_s_barrier();
        }
    } else {
        // ================= CONSUMER (waves 8-15) =================
        const int cw = wv - 8;             // rows 2cw, 2cw+1 of each strip
        for (int t = 0; t <= NT; ++t) {
            if (t > 0) {
                const int pbuf = (t - 1) & 1;
                #pragma unroll
                for (int rr = 0; rr < 2; ++rr) {
                    const int r = cw * 2 + rr;
                    float rs = 0.f;
                    #pragma unroll
                    for (int w8 = 0; w8 < 8; ++w8) rs += rsum_lds[pbuf][w8][r];
                    const float rinv = 1.0f / rs;
                    float* orow = out + outbase
                                + (size_t)(qchunk * 256 + (t - 1) * 16 + r) * SEQ;
                    #pragma unroll
                    for (int ii = 0; ii < 8; ++ii) {
                        half4 hv = *(const half4*)&p[pbuf][r][ii * 256 + l * 4];
                        f32x4 v;
                        v[0] = (float)hv[0] * rinv; v[1] = (float)hv[1] * rinv;
                        v[2] = (float)hv[2] * rinv; v[3] = (float)hv[3] * rinv;
                        __builtin_nontemporal_store(v, (f32x4*)(orow + ii * 256 + l * 4));
                    }
                }
            }
            asm volatile("s_waitcnt lgkmcnt(0)" ::: "memory");
            __builtin_amdgcn_s_barrier();
        }
    }
}

extern "C" void kernel_launch(void* const* d_in, const int* in_sizes, int n_in,
                              void* d_out, int out_size, void* d_ws, size_t ws_size,
                              hipStream_t stream) {
    const float* x  = (const float*)d_in[0];   // [2,2048,1024]
    const float* Wq = (const float*)d_in[1];   // [1024,1024]
    const float* bq = (const float*)d_in[2];   // [1024]
    float* out = (float*)d_out;                // [2,16,2048,2048]

    _Float16* xh = (_Float16*)d_ws;                    // 8 MB
    _Float16* qh = xh + (size_t)4 * 1024 * 1024;       // 8 MB
    _Float16* wt = qh + (size_t)4 * 1024 * 1024;       // 2 MB

    const int nx = NB * SEQ * HIDDEN;  // 4194304
    cast_x<<<nx / (256 * 4), 256, 0, stream>>>(x, xh, nx);
    cast_wt<<<dim3(32, 32), dim3(32, 8), 0, stream>>>(Wq, wt);
    proj_gemm<<<dim3(NB * SEQ / 128, HIDDEN / 128), 512, 0, stream>>>(xh, wt, bq, qh);
    scores_softmax<<<256, 1024, 0, stream>>>(qh, out);
}

// Round 9
// 131.125 us; speedup vs baseline: 2.7857x; 1.0018x over previous
//
#include <hip/hip_runtime.h>

#define HIDDEN 1024
#define SEQ 2048
#define NB 2
#define PSTRIDE 2052  // halfs per LDS p-row: 2048 + 4 pad
#define NT 16         // strips per block

typedef _Float16 half8 __attribute__((ext_vector_type(8)));
typedef _Float16 half4 __attribute__((ext_vector_type(4)));
typedef float f32x4 __attribute__((ext_vector_type(4)));

// global -> LDS direct staging, 16 B/lane (dest = wave-uniform base + lane*16)
#define GL2LDS(gp, lp) __builtin_amdgcn_global_load_lds( \
    (const __attribute__((address_space(1))) void*)(gp), \
    (__attribute__((address_space(3))) void*)(lp), 16, 0, 0)

// ---------------- cast + transpose Wq: wt[n][k] = Wq[k][n] ----------------
__global__ __launch_bounds__(256) void cast_wt(const float* __restrict__ w,
                                               _Float16* __restrict__ wt) {
    __shared__ float tile[32][33];
    int bx = blockIdx.x * 32, by = blockIdx.y * 32;
    int tx = threadIdx.x, ty = threadIdx.y;   // (32, 8)
    #pragma unroll
    for (int i = 0; i < 32; i += 8)
        tile[ty + i][tx] = w[(by + ty + i) * HIDDEN + bx + tx];
    __syncthreads();
    #pragma unroll
    for (int i = 0; i < 32; i += 8)
        wt[(bx + ty + i) * HIDDEN + by + tx] = (_Float16)tile[tx][ty + i];
}

// ---------------- projection GEMM: Q = x @ Wq + bq ----------------
// 128x128 tile, BK=64, 512 thr = 8 waves (2x4, wave-tile 64x32).
// A staged from fp32 x with in-register cvt + ds_write_b128 into the XOR-
// swizzled layout (swizzle on the WRITE address, matching the frag reads).
// B staged via global_load_lds width=16 (linear LDS dest, pre-swizzled
// global source slot) — both-sides-or-neither discipline per operand.
__global__ __launch_bounds__(512) void proj_gemm(const float* __restrict__ X,
                                                 const _Float16* __restrict__ Bt,
                                                 const float* __restrict__ bias,
                                                 _Float16* __restrict__ Q) {
    __shared__ _Float16 As[128 * 64];
    __shared__ _Float16 Bs[128 * 64];
    const int m0 = blockIdx.x * 128;
    const int n0 = blockIdx.y * 128;
    const int tid = threadIdx.x;
    const int w = tid >> 6, l = tid & 63;
    const int wm = w >> 2, wn = w & 3;           // 2x4 waves: 64-row x 32-col tiles
    const int lrow = l & 15, lkslot = l >> 4;    // frag: k-offset = lkslot*8

    // B staging coords: within a 1 KB chunk (8 rows x 8 slots), lane l covers
    // row chunk*8 + l/8, 16B slot l%8.
    const int srow = l >> 3, sslot = l & 7;

    f32x4 acc[4][2] = {};

    for (int k0 = 0; k0 < HIDDEN; k0 += 64) {
        __syncthreads();
        // ---- B: global_load_lds, linear dest, source slot pre-swizzled ----
        #pragma unroll
        for (int j = 0; j < 2; ++j) {
            const int chunk = w * 2 + j;              // 0..15
            const int r = chunk * 8 + srow;           // 0..127
            const int gslot = sslot ^ (r & 7);
            GL2LDS(&Bt[(size_t)(n0 + r) * HIDDEN + k0 + gslot * 8], Bs + chunk * 512);
        }
        // ---- A: fp32 load + cvt + swizzled ds_write ----
        #pragma unroll
        for (int it = 0; it < 2; ++it) {
            const int id = it * 512 + tid;
            const int row = id >> 3, slot = id & 7;
            const float* src = &X[(size_t)(m0 + row) * HIDDEN + k0 + slot * 8];
            f32x4 v0 = *(const f32x4*)src;
            f32x4 v1 = *(const f32x4*)(src + 4);
            half8 hv;
            hv[0] = (_Float16)v0[0]; hv[1] = (_Float16)v0[1];
            hv[2] = (_Float16)v0[2]; hv[3] = (_Float16)v0[3];
            hv[4] = (_Float16)v1[0]; hv[5] = (_Float16)v1[1];
            hv[6] = (_Float16)v1[2]; hv[7] = (_Float16)v1[3];
            *(half8*)&As[row * 64 + (slot ^ (row & 7)) * 8] = hv;
        }
        __syncthreads();   // drains GL2LDS (vmcnt) + ds_writes (lgkm)
        #pragma unroll
        for (int kk = 0; kk < 64; kk += 32) {
            const int csb = kk >> 3;                  // 0 or 4
            half8 af[4], bf[2];
            #pragma unroll
            for (int m = 0; m < 4; ++m) {
                const int R = wm * 64 + m * 16 + lrow;
                const int slot = (csb + lkslot) ^ (R & 7);
                af[m] = *(const half8*)&As[R * 64 + slot * 8];
            }
            #pragma unroll
            for (int n = 0; n < 2; ++n) {
                const int R = wn * 32 + n * 16 + lrow;
                const int slot = (csb + lkslot) ^ (R & 7);
                bf[n] = *(const half8*)&Bs[R * 64 + slot * 8];
            }
            #pragma unroll
            for (int m = 0; m < 4; ++m)
                #pragma unroll
                for (int n = 0; n < 2; ++n)
                    acc[m][n] = __builtin_amdgcn_mfma_f32_16x16x32_f16(af[m], bf[n], acc[m][n], 0, 0, 0);
        }
    }
    const int lr4 = (l >> 4) * 4, lc = l & 15;
    #pragma unroll
    for (int n = 0; n < 2; ++n) {
        int gcol = n0 + wn * 32 + n * 16 + lc;
        float b = bias[gcol];
        #pragma unroll
        for (int m = 0; m < 4; ++m) {
            #pragma unroll
            for (int r = 0; r < 4; ++r) {
                int grow = m0 + wm * 64 + m * 16 + lr4 + r;
                Q[(size_t)grow * HIDDEN + gcol] = (_Float16)(acc[m][n][r] + b);
            }
        }
    }
}

// ---------------- fused scores + softmax: producer/consumer wave specialization ----------------
// 256 blocks (1/CU) x 1024 thr = 16 waves. Waves 0-7 PRODUCE: global K/Q loads
// -> MFMA -> exp -> fp16 pack -> ds_write into double-buffered 16x2048 p-tile.
// Waves 8-15 CONSUME: ds_read -> *rinv -> contiguous non-temporal f32x4 stores
// (1 KB/wave-instr, L2-bypassing). vmcnt is per-wave: producers' load waits
// never sit behind stores; consumers never wait vmcnt at all. Phases linked by
// lgkmcnt(0)+s_barrier only, so NT stores drain across the next strip's compute.
// p = exp(e/8 - 8); the shift cancels in normalization.
__global__ __launch_bounds__(1024, 4) void scores_softmax(const _Float16* __restrict__ Qh,
                                                          float* __restrict__ out) {
    __shared__ __align__(16) _Float16 p[2][16][PSTRIDE];
    __shared__ float rsum_lds[2][8][16];

    // raw&7 = XCD (round-robin dispatch assumption): all 8 q-chunks of a (b,h)
    // land on one XCD; 4 slices x 256 KB = 1 MB per XCD L2, never store-thrashed.
    const int raw = blockIdx.x;            // 0..255
    const int xcd = raw & 7, i = raw >> 3; // i: 0..31
    const int bh = xcd * 4 + (i >> 3);     // 0..31
    const int qchunk = i & 7;              // rows [qchunk*256, +256)
    const int b = bh >> 4, h = bh & 15;

    const int tid = threadIdx.x;
    const int wv = tid >> 6;               // 0..15
    const int l = tid & 63;
    const int lq = l & 15, lg = l >> 4;
    const int hoff = h * 64;
    const _Float16* qbase = Qh + (size_t)b * SEQ * HIDDEN;
    const size_t outbase = (size_t)(b * 16 + h) * SEQ * SEQ;

    if (wv < 8) {
        // ================= PRODUCER (waves 0-7) =================
        const int pw = wv;
        const _Float16* kbase = qbase + (size_t)(pw * 256 + lq) * HIDDEN + hoff + lg * 8;
        for (int t = 0; t <= NT; ++t) {
            if (t < NT) {
                const int buf = t & 1;
                const int q0 = qchunk * 256 + t * 16;
                const _Float16* qp = qbase + (size_t)(q0 + lq) * HIDDEN + hoff + lg * 8;
                const half8 bq0 = *(const half8*)qp;
                const half8 bq1 = *(const half8*)(qp + 32);
                float rsum = 0.f;
                #pragma unroll
                for (int s = 0; s < 16; ++s) {
                    const _Float16* a = kbase + (size_t)s * 16 * HIDDEN;
                    half8 ka = *(const half8*)a;
                    half8 kb = *(const half8*)(a + 32);
                    f32x4 acc = {};
                    acc = __builtin_amdgcn_mfma_f32_16x16x32_f16(ka, bq0, acc, 0, 0, 0);
                    acc = __builtin_amdgcn_mfma_f32_16x16x32_f16(kb, bq1, acc, 0, 0, 0);
                    // C layout: col(q)=lane&15, row(k)=lg*4+reg
                    float e0 = exp2f(fmaf(acc[0], 0.18033688011f, -11.54156033f));
                    float e1 = exp2f(fmaf(acc[1], 0.18033688011f, -11.54156033f));
                    float e2 = exp2f(fmaf(acc[2], 0.18033688011f, -11.54156033f));
                    float e3 = exp2f(fmaf(acc[3], 0.18033688011f, -11.54156033f));
                    rsum += (e0 + e1) + (e2 + e3);
                    half4 hv;
                    hv[0] = (_Float16)e0; hv[1] = (_Float16)e1;
                    hv[2] = (_Float16)e2; hv[3] = (_Float16)e3;
                    *(half4*)&p[buf][lq][pw * 256 + s * 16 + lg * 4] = hv;
                }
                rsum += __shfl_xor(rsum, 16);
                rsum += __shfl_xor(rsum, 32);
                if (l < 16) rsum_lds[buf][pw][l] = rsum;
            }
            asm volatile("s_waitcnt lgkmcnt(0)" ::: "memory");
            __builtin_amdgcn_s_barrier();
        }
    } else {
        // ================= CONSUMER (waves 8-15) =================
        const int cw = wv - 8;             // rows 2cw, 2cw+1 of each strip
        for (int t = 0; t <= NT; ++t) {
            if (t > 0) {
                const int pbuf = (t - 1) & 1;
                #pragma unroll
                for (int rr = 0; rr < 2; ++rr) {
                    const int r = cw * 2 + rr;
                    float rs = 0.f;
                    #pragma unroll
                    for (int w8 = 0; w8 < 8; ++w8) rs += rsum_lds[pbuf][w8][r];
                    const float rinv = 1.0f / rs;
                    float* orow = out + outbase
                                + (size_t)(qchunk * 256 + (t - 1) * 16 + r) * SEQ;
                    #pragma unroll
                    for (int ii = 0; ii < 8; ++ii) {
                        half4 hv = *(const half4*)&p[pbuf][r][ii * 256 + l * 4];
                        f32x4 v;
                        v[0] = (float)hv[0] * rinv; v[1] = (float)hv[1] * rinv;
                        v[2] = (float)hv[2] * rinv; v[3] = (float)hv[3] * rinv;
                        __builtin_nontemporal_store(v, (f32x4*)(orow + ii * 256 + l * 4));
                    }
                }
            }
            asm volatile("s_waitcnt lgkmcnt(0)" ::: "memory");
            __builtin_amdgcn_s_barrier();
        }
    }
}

extern "C" void kernel_launch(void* const* d_in, const int* in_sizes, int n_in,
                              void* d_out, int out_size, void* d_ws, size_t ws_size,
                              hipStream_t stream) {
    const float* x  = (const float*)d_in[0];   // [2,2048,1024]
    const float* Wq = (const float*)d_in[1];   // [1024,1024]
    const float* bq = (const float*)d_in[2];   // [1024]
    float* out = (float*)d_out;                // [2,16,2048,2048]

    _Float16* qh = (_Float16*)d_ws;                    // 8 MB
    _Float16* wt = qh + (size_t)4 * 1024 * 1024;       // 2 MB

    cast_wt<<<dim3(32, 32), dim3(32, 8), 0, stream>>>(Wq, wt);
    proj_gemm<<<dim3(NB * SEQ / 128, HIDDEN / 128), 512, 0, stream>>>(x, wt, bq, qh);
    scores_softmax<<<256, 1024, 0, stream>>>(qh, out);
}